// Round 7
// baseline (95.631 us; speedup 1.0000x reference)
//
#include <hip/hip_runtime.h>

#define T_ 16
#define B_ 32
#define N_ 4096
#define NT 20
#define F_ 25
#define H_ 8
#define HID_ 128
#define PSTR 9               // padded LDS pool stride (spreads banks across ty rows)
#define SEGF_ (NT*H_)        // 160
#define BT 512               // threads per block; one block per (t,b)
#define NSUB (N_/BT)         // 8 chunks of 512 points
#define CF (BT*F_)           // 12800 floats per chunk

typedef __attribute__((address_space(1))) const void GV;
typedef __attribute__((address_space(3))) void LV;

// async global->LDS DMA (no VGPR round-trip); linear wave-uniform-base + lane*size.
__device__ __forceinline__ void g2l16(const float* g, float* l) {
  __builtin_amdgcn_global_load_lds((GV*)g, (LV*)l, 16, 0, 0);
}
__device__ __forceinline__ void g2l4(const float* g, float* l) {
  __builtin_amdgcn_global_load_lds((GV*)g, (LV*)l, 4, 0, 0);
}

// bf16 pack/unpack (values nonneg finite: relu outputs)
__device__ __forceinline__ unsigned f2bf(float x) {
  unsigned u = __float_as_uint(x);
  u += 0x7fffu + ((u >> 16) & 1u);
  return u >> 16;
}
__device__ __forceinline__ float bf2f(unsigned s) { return __uint_as_float(s << 16); }

// Tiny fully-unrolled MLP layer: out = relu(in @ W + b), W is (NI x 8) row-major.
template<int NI>
__device__ __forceinline__ void layer(const float* in, const float* __restrict__ W,
                                      const float* __restrict__ b, float* out) {
#pragma unroll
  for (int j = 0; j < H_; j++) {
    float a = b[j];
#pragma unroll
    for (int f = 0; f < NI; f++) a = fmaf(in[f], W[f*H_ + j], a);
    out[j] = fmaxf(a, 0.0f);
  }
}

// One block per (t,b). Double-buffered LDS staging with counted vmcnt (T3/T4):
// loads for chunk S+1/S+2 stay in flight across the per-chunk barriers — vmcnt
// never drains to 0 in the loop. h3 (bf16-packed) + ty stay in registers across
// the pool1 barrier (literal indices via macros). Single dispatch, no workspace.
extern "C" __global__ __launch_bounds__(BT, 2)
void kFused(const float* __restrict__ pts,
            const float* __restrict__ W1, const float* __restrict__ b1,
            const float* __restrict__ W2, const float* __restrict__ b2,
            const float* __restrict__ W3, const float* __restrict__ b3,
            const float* __restrict__ W4, const float* __restrict__ b4,
            const float* __restrict__ W5, const float* __restrict__ b5,
            const float* __restrict__ W6, const float* __restrict__ b6,
            const float* __restrict__ Wout, const float* __restrict__ bout,
            float* __restrict__ out)
{
  __shared__ float xs[2][CF];         // 2 x 51.2 KB staging (1 block/CU)
  __shared__ int lp1[NT*PSTR];        // pools: nonneg float bits, int max == float max
  __shared__ int lp2[NT*PSTR];
  const int tid = threadIdx.x;
  const int tb = blockIdx.x;
  if (tid < NT*PSTR) { lp1[tid] = 0; lp2[tid] = 0; }

  const float* base = pts + (size_t)tb * (N_*F_);

#define ISSUE(S, BUF)                                                    \
  {                                                                      \
    const float* gc = base + (S)*CF;                                     \
    float* lb = xs[BUF];                                                 \
    _Pragma("unroll")                                                    \
    for (int k = 0; k < 6; k++)                                          \
      g2l16(gc + (tid + k*BT)*4, lb + (tid + k*BT)*4);                   \
    g2l4(gc + 6*4*BT + tid, lb + 6*4*BT + tid);                          \
  }

  uint4 h3p[NSUB];                     // bf16x8 per point — literal indices only
  int   tyv[NSUB];

  ISSUE(0, 0)
  ISSUE(1, 1)

  // Per chunk: 7 loads/thread. Outstanding at loop head = {S, S+1} = 14 ->
  // vmcnt(7) completes chunk S, keeps S+1 in flight. Tail: S=7 waits vmcnt(0).
#define PH1(S, WN, DOISS)                                                \
  {                                                                      \
    asm volatile("s_waitcnt vmcnt(" #WN ")" ::: "memory");               \
    __builtin_amdgcn_sched_barrier(0);                                   \
    __builtin_amdgcn_s_barrier();      /* chunk S resident for all */    \
    __builtin_amdgcn_sched_barrier(0);                                   \
    float xv[F_];                                                        \
    const float* xb = xs[(S)&1];                                         \
    _Pragma("unroll")                                                    \
    for (int f = 0; f < F_; f++) xv[f] = xb[tid*F_ + f];                 \
    asm volatile("s_waitcnt lgkmcnt(0)" ::: "memory");                   \
    __builtin_amdgcn_sched_barrier(0);                                   \
    __builtin_amdgcn_s_barrier();      /* all reads done: buf free */    \
    __builtin_amdgcn_sched_barrier(0);                                   \
    if (DOISS) ISSUE((S)+2, (S)&1)                                       \
    int ty = 0; float best = xv[4];                                      \
    _Pragma("unroll")                                                    \
    for (int k = 1; k < NT; k++)                                         \
      if (xv[4+k] > best) { best = xv[4+k]; ty = k; }                    \
    const bool valid = (xv[F_-1] != 0.0f);                               \
    float t1[H_], t2[H_];                                                \
    layer<F_>(xv, W1, b1, t1);                                           \
    layer<H_>(t1, W2, b2, t2);                                           \
    layer<H_>(t2, W3, b3, t1);                                           \
    if (!valid) {                                                        \
      _Pragma("unroll")                                                  \
      for (int j = 0; j < H_; j++) t1[j] = 0.0f;                         \
    }                                                                    \
    h3p[S].x = f2bf(t1[0]) | (f2bf(t1[1]) << 16);                        \
    h3p[S].y = f2bf(t1[2]) | (f2bf(t1[3]) << 16);                        \
    h3p[S].z = f2bf(t1[4]) | (f2bf(t1[5]) << 16);                        \
    h3p[S].w = f2bf(t1[6]) | (f2bf(t1[7]) << 16);                        \
    tyv[S] = valid ? ty : -1;                                            \
    if (valid) {                                                         \
      _Pragma("unroll")                                                  \
      for (int j = 0; j < H_; j++)                                       \
        atomicMax(&lp1[ty*PSTR + j], __float_as_int(t1[j]));             \
    }                                                                    \
  }

  PH1(0,7,1) PH1(1,7,1) PH1(2,7,1) PH1(3,7,1)
  PH1(4,7,1) PH1(5,7,1) PH1(6,7,0) PH1(7,0,0)

  __syncthreads();                     // pool1 final (atomics visible)

#define PH2(S)                                                           \
  {                                                                      \
    const int ty = tyv[S];                                               \
    if (ty >= 0) {                                                       \
      float x16[2*H_];                                                   \
      x16[0] = bf2f(h3p[S].x & 0xffffu); x16[1] = bf2f(h3p[S].x >> 16);  \
      x16[2] = bf2f(h3p[S].y & 0xffffu); x16[3] = bf2f(h3p[S].y >> 16);  \
      x16[4] = bf2f(h3p[S].z & 0xffffu); x16[5] = bf2f(h3p[S].z >> 16);  \
      x16[6] = bf2f(h3p[S].w & 0xffffu); x16[7] = bf2f(h3p[S].w >> 16);  \
      _Pragma("unroll")                                                  \
      for (int j = 0; j < H_; j++)                                       \
        x16[H_+j] = __int_as_float(lp1[ty*PSTR + j]);                    \
      float t1[H_], t2[H_];                                              \
      layer<2*H_>(x16, W4, b4, t1);                                      \
      layer<H_>(t1, W5, b5, t2);                                         \
      layer<H_>(t2, W6, b6, t1);                                         \
      _Pragma("unroll")                                                  \
      for (int j = 0; j < H_; j++)                                       \
        atomicMax(&lp2[ty*PSTR + j], __float_as_int(t1[j]));             \
    }                                                                    \
  }

  PH2(0) PH2(1) PH2(2) PH2(3) PH2(4) PH2(5) PH2(6) PH2(7)

  __syncthreads();                     // pool2 final

  // ---- Phase 3: out[tb,:] = relu(pooled2 @ Wout + bout) ----
  if (tid < HID_) {
    float a = bout[tid];
#pragma unroll 4
    for (int k = 0; k < SEGF_; k++) {
      const float v = __int_as_float(lp2[(k >> 3)*PSTR + (k & 7)]);
      a = fmaf(v, Wout[k*HID_ + tid], a);
    }
    out[tb*HID_ + tid] = fmaxf(a, 0.0f);
  }
#undef ISSUE
#undef PH1
#undef PH2
}

extern "C" void kernel_launch(void* const* d_in, const int* in_sizes, int n_in,
                              void* d_out, int out_size, void* d_ws, size_t ws_size,
                              hipStream_t stream) {
  const float* pts  = (const float*)d_in[0];
  const float* W1   = (const float*)d_in[1];  const float* b1 = (const float*)d_in[2];
  const float* W2   = (const float*)d_in[3];  const float* b2 = (const float*)d_in[4];
  const float* W3   = (const float*)d_in[5];  const float* b3 = (const float*)d_in[6];
  const float* W4   = (const float*)d_in[7];  const float* b4 = (const float*)d_in[8];
  const float* W5   = (const float*)d_in[9];  const float* b5 = (const float*)d_in[10];
  const float* W6   = (const float*)d_in[11]; const float* b6 = (const float*)d_in[12];
  const float* Wout = (const float*)d_in[13]; const float* bout = (const float*)d_in[14];
  float* out = (float*)d_out;

  kFused<<<T_*B_, BT, 0, stream>>>(pts, W1, b1, W2, b2, W3, b3,
                                   W4, b4, W5, b5, W6, b6, Wout, bout, out);
}

// Round 8
// 88.746 us; speedup vs baseline: 1.0776x; 1.0776x over previous
//
#include <hip/hip_runtime.h>

#define T_ 16
#define B_ 32
#define N_ 4096
#define NT 20
#define F_ 25
#define H_ 8
#define HID_ 128
#define PSTR 9               // padded LDS pool stride
#define SEGF_ (NT*H_)        // 160
#define BT 512               // threads per block
#define NW 8                 // waves per block
#define WPTS 64              // points per wave-chunk (1/lane)
#define WFL (WPTS*F_)        // 1600 floats per wave-chunk slice
#define CF (BT*F_)           // 12800 floats per block-chunk
#define NCHUNK 16            // 2 slots x 8 chunks

typedef __attribute__((address_space(1))) const void GV;
typedef __attribute__((address_space(3))) void LV;

__device__ __forceinline__ void g2l16(const float* g, float* l) {
  __builtin_amdgcn_global_load_lds((GV*)g, (LV*)l, 16, 0, 0);
}
__device__ __forceinline__ void g2l4(const float* g, float* l) {
  __builtin_amdgcn_global_load_lds((GV*)g, (LV*)l, 4, 0, 0);
}

// bf16 pack/unpack (values nonneg finite: relu outputs)
__device__ __forceinline__ unsigned f2bf(float x) {
  unsigned u = __float_as_uint(x);
  u += 0x7fffu + ((u >> 16) & 1u);
  return u >> 16;
}
__device__ __forceinline__ float bf2f(unsigned s) { return __uint_as_float(s << 16); }

template<int NI>
__device__ __forceinline__ void layer(const float* in, const float* __restrict__ W,
                                      const float* __restrict__ b, float* out) {
#pragma unroll
  for (int j = 0; j < H_; j++) {
    float a = b[j];
#pragma unroll
    for (int f = 0; f < NI; f++) a = fmaf(in[f], W[f*H_ + j], a);
    out[j] = fmaxf(a, 0.0f);
  }
}

// lgkm-only barrier: does NOT drain vmcnt -> global_load_lds prefetches stay in flight.
#define LBAR()                                                  \
  { asm volatile("s_waitcnt lgkmcnt(0)" ::: "memory");          \
    __builtin_amdgcn_sched_barrier(0);                          \
    __builtin_amdgcn_s_barrier();                               \
    __builtin_amdgcn_sched_barrier(0); }

// One block = 2 (t,b) slots, 256 blocks = 1/CU. Phase 1 is wave-autonomous:
// each wave streams its own 64-point chunks through its private LDS slice with
// per-wave counted vmcnt (no block barriers). 3 buffers = depth-2 prefetch.
// Slot 0's MLP2+GEMV overlap slot 1's streaming (lgkm-only barriers).
extern "C" __global__ __launch_bounds__(BT, 2)
void kFused(const float* __restrict__ pts,
            const float* __restrict__ W1, const float* __restrict__ b1,
            const float* __restrict__ W2, const float* __restrict__ b2,
            const float* __restrict__ W3, const float* __restrict__ b3,
            const float* __restrict__ W4, const float* __restrict__ b4,
            const float* __restrict__ W5, const float* __restrict__ b5,
            const float* __restrict__ W6, const float* __restrict__ b6,
            const float* __restrict__ Wout, const float* __restrict__ bout,
            float* __restrict__ out)
{
  __shared__ float xs[3][NW][WFL];    // 153.6 KB: 3 buffers x 8 wave slices
  __shared__ int lp1[NT*PSTR];        // pools: nonneg float bits, int max == float max
  __shared__ int lp2[NT*PSTR];
  const int tid  = threadIdx.x;
  const int wid  = tid >> 6;
  const int lane = tid & 63;
  if (tid < NT*PSTR) { lp1[tid] = 0; lp2[tid] = 0; }
  __syncthreads();                    // nothing in flight yet; full drain harmless

  // two consecutive (t,b) slots per block
  const float* gblk = pts + (size_t)blockIdx.x * (2*N_*F_);

#define ISSUE(C)                                                         \
  {                                                                      \
    const float* gc = gblk + (size_t)(C)*CF + wid*WFL;                   \
    float* lb = &xs[(C)%3][wid][0];                                      \
    _Pragma("unroll")                                                    \
    for (int k = 0; k < 6; k++)                                          \
      g2l16(gc + k*256 + lane*4, lb + k*256 + lane*4);                   \
    g2l4(gc + 1536 + lane, lb + 1536 + lane);                            \
  }

  uint4 h3p[NW];                       // bf16x8 per point; literal indices only
  int   tyv[NW];

  ISSUE(0)
  ISSUE(1)

  // Per wave-chunk: 7 loads. Head outstanding = {C, C+1} = 14; vmcnt(7) -> C landed.
  // Reads drained (lgkmcnt(0), per-wave) before ISSUE(C+2) reuses buffer (C+2)%3.
#define STEP(C, WN, DOISS)                                               \
  {                                                                      \
    asm volatile("s_waitcnt vmcnt(" #WN ")" ::: "memory");               \
    __builtin_amdgcn_sched_barrier(0);                                   \
    float xv[F_];                                                        \
    const float* xb = &xs[(C)%3][wid][lane*F_];                          \
    _Pragma("unroll")                                                    \
    for (int f = 0; f < F_; f++) xv[f] = xb[f];                          \
    asm volatile("s_waitcnt lgkmcnt(0)" ::: "memory");                   \
    __builtin_amdgcn_sched_barrier(0);                                   \
    if (DOISS) ISSUE((C)+2)                                              \
    int ty = 0; float best = xv[4];                                      \
    _Pragma("unroll")                                                    \
    for (int k = 1; k < NT; k++)                                         \
      if (xv[4+k] > best) { best = xv[4+k]; ty = k; }                    \
    const bool valid = (xv[F_-1] != 0.0f);                               \
    float t1[H_], t2[H_];                                                \
    layer<F_>(xv, W1, b1, t1);                                           \
    layer<H_>(t1, W2, b2, t2);                                           \
    layer<H_>(t2, W3, b3, t1);                                           \
    if (!valid) {                                                        \
      _Pragma("unroll")                                                  \
      for (int j = 0; j < H_; j++) t1[j] = 0.0f;                         \
    }                                                                    \
    h3p[(C)&7].x = f2bf(t1[0]) | (f2bf(t1[1]) << 16);                    \
    h3p[(C)&7].y = f2bf(t1[2]) | (f2bf(t1[3]) << 16);                    \
    h3p[(C)&7].z = f2bf(t1[4]) | (f2bf(t1[5]) << 16);                    \
    h3p[(C)&7].w = f2bf(t1[6]) | (f2bf(t1[7]) << 16);                    \
    tyv[(C)&7] = valid ? ty : -1;                                        \
    if (valid) {                                                         \
      _Pragma("unroll")                                                  \
      for (int j = 0; j < H_; j++)                                       \
        atomicMax(&lp1[ty*PSTR + j], __float_as_int(t1[j]));             \
    }                                                                    \
  }

#define PH2(S)                                                           \
  {                                                                      \
    const int ty = tyv[S];                                               \
    if (ty >= 0) {                                                       \
      float x16[2*H_];                                                   \
      x16[0] = bf2f(h3p[S].x & 0xffffu); x16[1] = bf2f(h3p[S].x >> 16);  \
      x16[2] = bf2f(h3p[S].y & 0xffffu); x16[3] = bf2f(h3p[S].y >> 16);  \
      x16[4] = bf2f(h3p[S].z & 0xffffu); x16[5] = bf2f(h3p[S].z >> 16);  \
      x16[6] = bf2f(h3p[S].w & 0xffffu); x16[7] = bf2f(h3p[S].w >> 16);  \
      _Pragma("unroll")                                                  \
      for (int j = 0; j < H_; j++)                                       \
        x16[H_+j] = __int_as_float(lp1[ty*PSTR + j]);                    \
      float t1[H_], t2[H_];                                              \
      layer<2*H_>(x16, W4, b4, t1);                                      \
      layer<H_>(t1, W5, b5, t2);                                         \
      layer<H_>(t2, W6, b6, t1);                                         \
      _Pragma("unroll")                                                  \
      for (int j = 0; j < H_; j++)                                       \
        atomicMax(&lp2[ty*PSTR + j], __float_as_int(t1[j]));             \
    }                                                                    \
  }

#define PH3(SLOT)                                                        \
  if (tid < HID_) {                                                      \
    float a = bout[tid];                                                 \
    _Pragma("unroll 4")                                                  \
    for (int k = 0; k < SEGF_; k++) {                                    \
      const float v = __int_as_float(lp2[(k >> 3)*PSTR + (k & 7)]);      \
      a = fmaf(v, Wout[k*HID_ + tid], a);                                \
    }                                                                    \
    out[((size_t)blockIdx.x*2 + (SLOT))*HID_ + tid] = fmaxf(a, 0.0f);    \
  }

  // ---------------- slot 0: chunks 0..7 ----------------
  STEP(0,7,1) STEP(1,7,1) STEP(2,7,1) STEP(3,7,1)
  STEP(4,7,1) STEP(5,7,1) STEP(6,7,1) STEP(7,7,1)
  LBAR()                               // pool1(slot0) complete; chunks 8,9 in flight
  PH2(0) PH2(1) PH2(2) PH2(3) PH2(4) PH2(5) PH2(6) PH2(7)
  LBAR()                               // pool2(slot0) complete
  PH3(0)
  LBAR()                               // lp reads done -> safe to re-zero
  if (tid < NT*PSTR) { lp1[tid] = 0; lp2[tid] = 0; }
  LBAR()                               // zeros visible before slot1 atomics

  // ---------------- slot 1: chunks 8..15 ----------------
  STEP(8,7,1)  STEP(9,7,1)  STEP(10,7,1) STEP(11,7,1)
  STEP(12,7,1) STEP(13,7,1) STEP(14,7,0) STEP(15,0,0)
  LBAR()
  PH2(0) PH2(1) PH2(2) PH2(3) PH2(4) PH2(5) PH2(6) PH2(7)
  LBAR()
  PH3(1)

#undef ISSUE
#undef STEP
#undef PH2
#undef PH3
#undef LBAR
}

extern "C" void kernel_launch(void* const* d_in, const int* in_sizes, int n_in,
                              void* d_out, int out_size, void* d_ws, size_t ws_size,
                              hipStream_t stream) {
  const float* pts  = (const float*)d_in[0];
  const float* W1   = (const float*)d_in[1];  const float* b1 = (const float*)d_in[2];
  const float* W2   = (const float*)d_in[3];  const float* b2 = (const float*)d_in[4];
  const float* W3   = (const float*)d_in[5];  const float* b3 = (const float*)d_in[6];
  const float* W4   = (const float*)d_in[7];  const float* b4 = (const float*)d_in[8];
  const float* W5   = (const float*)d_in[9];  const float* b5 = (const float*)d_in[10];
  const float* W6   = (const float*)d_in[11]; const float* b6 = (const float*)d_in[12];
  const float* Wout = (const float*)d_in[13]; const float* bout = (const float*)d_in[14];
  float* out = (float*)d_out;

  kFused<<<T_*B_/2, BT, 0, stream>>>(pts, W1, b1, W2, b2, W3, b3,
                                     W4, b4, W5, b5, W6, b6, Wout, bout, out);
}

// Round 9
// 78.119 us; speedup vs baseline: 1.2242x; 1.1360x over previous
//
#include <hip/hip_runtime.h>

#define T_ 16
#define B_ 32
#define N_ 4096
#define NT 20
#define F_ 25
#define H_ 8
#define HID_ 128
#define PSTR 9               // padded LDS pool stride
#define SEGF_ (NT*H_)        // 160
#define BT 512               // threads per block; one block per (t,b)
#define NSUB (N_/BT)         // 8 chunks of 512 points
#define CF (BT*F_)           // 12800 floats per chunk

// LDS weight-cache layout (floats), columns contiguous (transposed):
#define W1T 0     // 8 cols x 28 (25 used, pad->16B)
#define B1O 224
#define W2T 232   // 8 cols x 8
#define B2O 296
#define W3T 304
#define B3O 368
#define W4T 376   // 8 cols x 16
#define B4O 504
#define W5T 512
#define B5O 576
#define W6T 584
#define B6O 648
#define WLF 656   // 2.62 KB

typedef __attribute__((address_space(1))) const void GV;
typedef __attribute__((address_space(3))) void LV;

__device__ __forceinline__ void g2l16(const float* g, float* l) {
  __builtin_amdgcn_global_load_lds((GV*)g, (LV*)l, 16, 0, 0);
}
__device__ __forceinline__ void g2l4(const float* g, float* l) {
  __builtin_amdgcn_global_load_lds((GV*)g, (LV*)l, 4, 0, 0);
}

// bf16 pack/unpack (values nonneg finite: relu outputs)
__device__ __forceinline__ unsigned f2bf(float x) {
  unsigned u = __float_as_uint(x);
  u += 0x7fffu + ((u >> 16) & 1u);
  return u >> 16;
}
__device__ __forceinline__ float bf2f(unsigned s) { return __uint_as_float(s << 16); }

// MLP layer reading weights from LDS (transposed, col stride STR): out = relu(in@W+b).
// Weight addresses are lane-uniform -> LDS broadcast reads, merged into b128.
template<int NI, int STR>
__device__ __forceinline__ void layerL(const float* in, const float* wcol,
                                       const float* bias, float* out) {
#pragma unroll
  for (int j = 0; j < H_; j++) {
    float a = bias[j];
#pragma unroll
    for (int f = 0; f < NI; f++) a = fmaf(in[f], wcol[j*STR + f], a);
    out[j] = fmaxf(a, 0.0f);
  }
}

// R6 structure (proven): one block per (t,b), single-buffer staged streaming with
// full-drain barriers, h3 bf16-packed in registers (literal indices), LDS pools.
// NEW: all MLP weights cached in LDS (transposed) to kill per-point s_load refills.
extern "C" __global__ __launch_bounds__(BT, 4)
void kFused(const float* __restrict__ pts,
            const float* __restrict__ W1, const float* __restrict__ b1,
            const float* __restrict__ W2, const float* __restrict__ b2,
            const float* __restrict__ W3, const float* __restrict__ b3,
            const float* __restrict__ W4, const float* __restrict__ b4,
            const float* __restrict__ W5, const float* __restrict__ b5,
            const float* __restrict__ W6, const float* __restrict__ b6,
            const float* __restrict__ Wout, const float* __restrict__ bout,
            float* __restrict__ out)
{
  __shared__ float xs[CF];            // 51.2 KB staging
  __shared__ float wl[WLF];           // 2.62 KB weight cache
  __shared__ int lp1[NT*PSTR];        // pools: nonneg float bits, int max == float max
  __shared__ int lp2[NT*PSTR];
  const int tid = threadIdx.x;
  const int tb = blockIdx.x;
  if (tid < NT*PSTR) { lp1[tid] = 0; lp2[tid] = 0; }

  // ---- fill weight cache (transposed: col j contiguous) ----
  {
    if (tid < 200) { int f = tid >> 3, j = tid & 7; wl[W1T + j*28 + f] = W1[tid]; }
    else if (tid < 264) { int i = tid - 200, f = i >> 3, j = i & 7; wl[W2T + j*8 + f] = W2[i]; }
    else if (tid < 328) { int i = tid - 264, f = i >> 3, j = i & 7; wl[W3T + j*8 + f] = W3[i]; }
    else if (tid < 456) { int i = tid - 328, f = i >> 3, j = i & 7; wl[W4T + j*16 + f] = W4[i]; }
    if (tid >= 456 && tid < 504) {
      int i = tid - 456;
      if (i < 8)       wl[B1O + i] = b1[i];
      else if (i < 16) wl[B2O + i - 8]  = b2[i - 8];
      else if (i < 24) wl[B3O + i - 16] = b3[i - 16];
      else if (i < 32) wl[B4O + i - 24] = b4[i - 24];
      else if (i < 40) wl[B5O + i - 32] = b5[i - 32];
      else             wl[B6O + i - 40] = b6[i - 40];
    }
    for (int i = tid; i < 64; i += BT) { int f = i >> 3, j = i & 7; wl[W5T + j*8 + f] = W5[i]; }
    for (int i = tid; i < 64; i += BT) { int f = i >> 3, j = i & 7; wl[W6T + j*8 + f] = W6[i]; }
  }

  const float* base = pts + (size_t)tb * (N_*F_);

#define ISSUE(S)                                                         \
  {                                                                      \
    const float* gc = base + (S)*CF;                                     \
    _Pragma("unroll")                                                    \
    for (int k = 0; k < 6; k++)                                          \
      g2l16(gc + (tid + k*BT)*4, xs + (tid + k*BT)*4);                   \
    g2l4(gc + 6*4*BT + tid, xs + 6*4*BT + tid);                          \
  }

  uint4 h3p[NSUB];                     // bf16x8 per point — literal indices only
  int   tyv[NSUB];

  ISSUE(0)

#define PH1(S)                                                           \
  {                                                                      \
    __syncthreads();  /* drains vmcnt -> chunk S in xs; wl/lp visible */ \
    float xv[F_];                                                        \
    _Pragma("unroll")                                                    \
    for (int f = 0; f < F_; f++) xv[f] = xs[tid*F_ + f];                 \
    __syncthreads();  /* all reads done -> xs reusable */                \
    if ((S) < NSUB-1) ISSUE((S)+1)                                       \
    int ty = 0; float best = xv[4];                                      \
    _Pragma("unroll")                                                    \
    for (int k = 1; k < NT; k++)                                         \
      if (xv[4+k] > best) { best = xv[4+k]; ty = k; }                    \
    const bool valid = (xv[F_-1] != 0.0f);                               \
    float t1[H_], t2[H_];                                                \
    layerL<F_,28>(xv, &wl[W1T], &wl[B1O], t1);                           \
    layerL<H_,8>(t1, &wl[W2T], &wl[B2O], t2);                            \
    layerL<H_,8>(t2, &wl[W3T], &wl[B3O], t1);                            \
    if (!valid) {                                                        \
      _Pragma("unroll")                                                  \
      for (int j = 0; j < H_; j++) t1[j] = 0.0f;                         \
    }                                                                    \
    h3p[S].x = f2bf(t1[0]) | (f2bf(t1[1]) << 16);                        \
    h3p[S].y = f2bf(t1[2]) | (f2bf(t1[3]) << 16);                        \
    h3p[S].z = f2bf(t1[4]) | (f2bf(t1[5]) << 16);                        \
    h3p[S].w = f2bf(t1[6]) | (f2bf(t1[7]) << 16);                        \
    tyv[S] = valid ? ty : -1;                                            \
    if (valid) {                                                         \
      _Pragma("unroll")                                                  \
      for (int j = 0; j < H_; j++)                                       \
        atomicMax(&lp1[ty*PSTR + j], __float_as_int(t1[j]));             \
    }                                                                    \
  }

  PH1(0) PH1(1) PH1(2) PH1(3) PH1(4) PH1(5) PH1(6) PH1(7)

  __syncthreads();                     // pool1 final

#define PH2(S)                                                           \
  {                                                                      \
    const int ty = tyv[S];                                               \
    if (ty >= 0) {                                                       \
      float x16[2*H_];                                                   \
      x16[0] = bf2f(h3p[S].x & 0xffffu); x16[1] = bf2f(h3p[S].x >> 16);  \
      x16[2] = bf2f(h3p[S].y & 0xffffu); x16[3] = bf2f(h3p[S].y >> 16);  \
      x16[4] = bf2f(h3p[S].z & 0xffffu); x16[5] = bf2f(h3p[S].z >> 16);  \
      x16[6] = bf2f(h3p[S].w & 0xffffu); x16[7] = bf2f(h3p[S].w >> 16);  \
      _Pragma("unroll")                                                  \
      for (int j = 0; j < H_; j++)                                       \
        x16[H_+j] = __int_as_float(lp1[ty*PSTR + j]);                    \
      float t1[H_], t2[H_];                                              \
      layerL<2*H_,16>(x16, &wl[W4T], &wl[B4O], t1);                      \
      layerL<H_,8>(t1, &wl[W5T], &wl[B5O], t2);                          \
      layerL<H_,8>(t2, &wl[W6T], &wl[B6O], t1);                          \
      _Pragma("unroll")                                                  \
      for (int j = 0; j < H_; j++)                                       \
        atomicMax(&lp2[ty*PSTR + j], __float_as_int(t1[j]));             \
    }                                                                    \
  }

  PH2(0) PH2(1) PH2(2) PH2(3) PH2(4) PH2(5) PH2(6) PH2(7)

  __syncthreads();                     // pool2 final

  // ---- Phase 3: out[tb,:] = relu(pooled2 @ Wout + bout) ----
  if (tid < HID_) {
    float a = bout[tid];
#pragma unroll 4
    for (int k = 0; k < SEGF_; k++) {
      const float v = __int_as_float(lp2[(k >> 3)*PSTR + (k & 7)]);
      a = fmaf(v, Wout[k*HID_ + tid], a);
    }
    out[tb*HID_ + tid] = fmaxf(a, 0.0f);
  }
#undef ISSUE
#undef PH1
#undef PH2
}

extern "C" void kernel_launch(void* const* d_in, const int* in_sizes, int n_in,
                              void* d_out, int out_size, void* d_ws, size_t ws_size,
                              hipStream_t stream) {
  const float* pts  = (const float*)d_in[0];
  const float* W1   = (const float*)d_in[1];  const float* b1 = (const float*)d_in[2];
  const float* W2   = (const float*)d_in[3];  const float* b2 = (const float*)d_in[4];
  const float* W3   = (const float*)d_in[5];  const float* b3 = (const float*)d_in[6];
  const float* W4   = (const float*)d_in[7];  const float* b4 = (const float*)d_in[8];
  const float* W5   = (const float*)d_in[9];  const float* b5 = (const float*)d_in[10];
  const float* W6   = (const float*)d_in[11]; const float* b6 = (const float*)d_in[12];
  const float* Wout = (const float*)d_in[13]; const float* bout = (const float*)d_in[14];
  float* out = (float*)d_out;

  kFused<<<T_*B_, BT, 0, stream>>>(pts, W1, b1, W2, b2, W3, b3,
                                   W4, b4, W5, b5, W6, b6, Wout, bout, out);
}

// Round 10
// 65.874 us; speedup vs baseline: 1.4517x; 1.1859x over previous
//
#include <hip/hip_runtime.h>

#define T_ 16
#define B_ 32
#define N_ 4096
#define NT 20
#define F_ 25
#define H_ 8
#define HID_ 128
#define PSTR 9               // padded LDS pool stride
#define SEGF_ (NT*H_)        // 160
#define BT 512               // threads per block; one block per (t,b)
#define NSUB (N_/BT)         // 8 chunks of 512 points
#define CF (BT*F_)           // 12800 floats per chunk
#define WSL 1600             // floats per wave slice (64 pts x 25)

typedef __attribute__((address_space(1))) const void GV;
typedef __attribute__((address_space(3))) void LV;

__device__ __forceinline__ void g2l16(const float* g, float* l) {
  __builtin_amdgcn_global_load_lds((GV*)g, (LV*)l, 16, 0, 0);
}
__device__ __forceinline__ void g2l4(const float* g, float* l) {
  __builtin_amdgcn_global_load_lds((GV*)g, (LV*)l, 4, 0, 0);
}

// bf16 pack/unpack (values nonneg finite: relu outputs)
__device__ __forceinline__ unsigned f2bf(float x) {
  unsigned u = __float_as_uint(x);
  u += 0x7fffu + ((u >> 16) & 1u);
  return u >> 16;
}
__device__ __forceinline__ float bf2f(unsigned s) { return __uint_as_float(s << 16); }

// Tiny fully-unrolled MLP layer: out = relu(in @ W + b), W is (NI x 8) row-major.
// W/b wave-uniform + compile-time indices -> scalar loads (R6 path; LDS cache was
// slower, R9: it saturates the per-CU LDS pipe).
template<int NI>
__device__ __forceinline__ void layer(const float* in, const float* __restrict__ W,
                                      const float* __restrict__ b, float* out) {
#pragma unroll
  for (int j = 0; j < H_; j++) {
    float a = b[j];
#pragma unroll
    for (int f = 0; f < NI; f++) a = fmaf(in[f], W[f*H_ + j], a);
    out[j] = fmaxf(a, 0.0f);
  }
}

// R6 structure with WAVE-PRIVATE staging: each wave DMAs + reads only its own
// 6.4 KB slice -> per-wave vmcnt/lgkm waits replace block barriers in the stream
// loop. Waves free-run => continuous HBM demand at 16 waves/CU (2 blocks/CU).
extern "C" __global__ __launch_bounds__(BT, 4)
void kFused(const float* __restrict__ pts,
            const float* __restrict__ W1, const float* __restrict__ b1,
            const float* __restrict__ W2, const float* __restrict__ b2,
            const float* __restrict__ W3, const float* __restrict__ b3,
            const float* __restrict__ W4, const float* __restrict__ b4,
            const float* __restrict__ W5, const float* __restrict__ b5,
            const float* __restrict__ W6, const float* __restrict__ b6,
            const float* __restrict__ Wout, const float* __restrict__ bout,
            float* __restrict__ out)
{
  __shared__ float xs[CF];            // 51.2 KB staging: 8 wave-private 6.4 KB slices
  __shared__ int lp1[NT*PSTR];        // pools: nonneg float bits, int max == float max
  __shared__ int lp2[NT*PSTR];
  const int tid  = threadIdx.x;
  const int wid  = tid >> 6;
  const int lane = tid & 63;
  const int tb = blockIdx.x;
  if (tid < NT*PSTR) { lp1[tid] = 0; lp2[tid] = 0; }
  __syncthreads();                    // pools zeroed before any atomics (pre-DMA)

  const float* base = pts + (size_t)tb * (N_*F_);
  float* lw = xs + wid*WSL;           // this wave's private slice

  // Wave-private DMA: instr k -> uniform base (lw + k*256) + lane*16B. Lane l's
  // point data = slice floats [l*25, l*25+25) is loaded by this wave only.
#define ISSUE(S)                                                         \
  {                                                                      \
    const float* gw = base + (S)*CF + wid*WSL;                           \
    _Pragma("unroll")                                                    \
    for (int k = 0; k < 6; k++)                                          \
      g2l16(gw + k*256 + lane*4, lw + k*256 + lane*4);                   \
    g2l4(gw + 1536 + lane, lw + 1536 + lane);                            \
  }

  uint4 h3p[NSUB];                     // bf16x8 per point — literal indices only
  int   tyv[NSUB];

  ISSUE(0)

  // Per-wave pipeline step: wait own slice (vmcnt only counts this wave's DMA),
  // read xv to regs, drain ds_reads, refill slice for S+1, then compute chunk S.
#define PH1(S)                                                           \
  {                                                                      \
    asm volatile("s_waitcnt vmcnt(0)" ::: "memory");                     \
    __builtin_amdgcn_sched_barrier(0);                                   \
    float xv[F_];                                                        \
    _Pragma("unroll")                                                    \
    for (int f = 0; f < F_; f++) xv[f] = lw[lane*F_ + f];                \
    asm volatile("s_waitcnt lgkmcnt(0)" ::: "memory");                   \
    __builtin_amdgcn_sched_barrier(0);                                   \
    if ((S) < NSUB-1) ISSUE((S)+1)                                       \
    int ty = 0; float best = xv[4];                                      \
    _Pragma("unroll")                                                    \
    for (int k = 1; k < NT; k++)                                         \
      if (xv[4+k] > best) { best = xv[4+k]; ty = k; }                    \
    const bool valid = (xv[F_-1] != 0.0f);                               \
    float t1[H_], t2[H_];                                                \
    layer<F_>(xv, W1, b1, t1);                                           \
    layer<H_>(t1, W2, b2, t2);                                           \
    layer<H_>(t2, W3, b3, t1);                                           \
    if (!valid) {                                                        \
      _Pragma("unroll")                                                  \
      for (int j = 0; j < H_; j++) t1[j] = 0.0f;                         \
    }                                                                    \
    h3p[S].x = f2bf(t1[0]) | (f2bf(t1[1]) << 16);                        \
    h3p[S].y = f2bf(t1[2]) | (f2bf(t1[3]) << 16);                        \
    h3p[S].z = f2bf(t1[4]) | (f2bf(t1[5]) << 16);                        \
    h3p[S].w = f2bf(t1[6]) | (f2bf(t1[7]) << 16);                        \
    tyv[S] = valid ? ty : -1;                                            \
    if (valid) {                                                         \
      _Pragma("unroll")                                                  \
      for (int j = 0; j < H_; j++)                                       \
        atomicMax(&lp1[ty*PSTR + j], __float_as_int(t1[j]));             \
    }                                                                    \
  }

  PH1(0) PH1(1) PH1(2) PH1(3) PH1(4) PH1(5) PH1(6) PH1(7)

  __syncthreads();                     // pool1 final (all waves' atomics visible)

#define PH2(S)                                                           \
  {                                                                      \
    const int ty = tyv[S];                                               \
    if (ty >= 0) {                                                       \
      float x16[2*H_];                                                   \
      x16[0] = bf2f(h3p[S].x & 0xffffu); x16[1] = bf2f(h3p[S].x >> 16);  \
      x16[2] = bf2f(h3p[S].y & 0xffffu); x16[3] = bf2f(h3p[S].y >> 16);  \
      x16[4] = bf2f(h3p[S].z & 0xffffu); x16[5] = bf2f(h3p[S].z >> 16);  \
      x16[6] = bf2f(h3p[S].w & 0xffffu); x16[7] = bf2f(h3p[S].w >> 16);  \
      _Pragma("unroll")                                                  \
      for (int j = 0; j < H_; j++)                                       \
        x16[H_+j] = __int_as_float(lp1[ty*PSTR + j]);                    \
      float t1[H_], t2[H_];                                              \
      layer<2*H_>(x16, W4, b4, t1);                                      \
      layer<H_>(t1, W5, b5, t2);                                         \
      layer<H_>(t2, W6, b6, t1);                                         \
      _Pragma("unroll")                                                  \
      for (int j = 0; j < H_; j++)                                       \
        atomicMax(&lp2[ty*PSTR + j], __float_as_int(t1[j]));             \
    }                                                                    \
  }

  PH2(0) PH2(1) PH2(2) PH2(3) PH2(4) PH2(5) PH2(6) PH2(7)

  __syncthreads();                     // pool2 final

  // ---- Phase 3: out[tb,:] = relu(pooled2 @ Wout + bout) ----
  if (tid < HID_) {
    float a = bout[tid];
#pragma unroll 4
    for (int k = 0; k < SEGF_; k++) {
      const float v = __int_as_float(lp2[(k >> 3)*PSTR + (k & 7)]);
      a = fmaf(v, Wout[k*HID_ + tid], a);
    }
    out[tb*HID_ + tid] = fmaxf(a, 0.0f);
  }
#undef ISSUE
#undef PH1
#undef PH2
}

extern "C" void kernel_launch(void* const* d_in, const int* in_sizes, int n_in,
                              void* d_out, int out_size, void* d_ws, size_t ws_size,
                              hipStream_t stream) {
  const float* pts  = (const float*)d_in[0];
  const float* W1   = (const float*)d_in[1];  const float* b1 = (const float*)d_in[2];
  const float* W2   = (const float*)d_in[3];  const float* b2 = (const float*)d_in[4];
  const float* W3   = (const float*)d_in[5];  const float* b3 = (const float*)d_in[6];
  const float* W4   = (const float*)d_in[7];  const float* b4 = (const float*)d_in[8];
  const float* W5   = (const float*)d_in[9];  const float* b5 = (const float*)d_in[10];
  const float* W6   = (const float*)d_in[11]; const float* b6 = (const float*)d_in[12];
  const float* Wout = (const float*)d_in[13]; const float* bout = (const float*)d_in[14];
  float* out = (float*)d_out;

  kFused<<<T_*B_, BT, 0, stream>>>(pts, W1, b1, W2, b2, W3, b3,
                                   W4, b4, W5, b5, W6, b6, Wout, bout, out);
}